// Round 1
// baseline (518.696 us; speedup 1.0000x reference)
//
#include <hip/hip_runtime.h>
#include <stdint.h>
#include <math.h>

// OTLoss: ft(4096x1024), fs(4096x1024) fp32 -> (loss, P[4096x4096], M[4096x4096])
//
// Pipeline:
//  1) row-normalize ft, fs -> bf16 A, B (ws)
//  2) M_raw = A @ B^T via mfma_f32_16x16x32_bf16, 128x128 tiles, global_load_lds
//     epilogue: atomic sum/sumsq (mean/std) + per-row max (ordered-uint atomicMax)
//     M_raw written into d_out's M slot (scratch-in-place)
//  3) stats: mean, inv_std (ddof=1)
//  4) buildK: M_out = (M_raw-mean)*inv_std in place; K = exp((M_raw-rowmax)*inv_std) fp16
//  5) Sinkhorn as diagonal scaling: P = diag(u) K diag(v)
//     per iter: u = r/(Kv)  [row matvec]; t = K^T u [col matvec, atomics];
//     upd: maxdev = max|v*t - c|; if <= eps -> done (freeze), else v = c/t
//  6) final: w = 1/(Kv); s = K^T w; P_ij = K_ij*w_i/s_j; loss = ||P - I||_F

#define NN 4096
#define DIM 1024
#define OT_ITERS 20
#define OT_EPS_F 1e-6f
#define RC (1.0f/4096.0f)

typedef __bf16 bf16_t;
typedef _Float16 half_t;
typedef __bf16 bf16x8 __attribute__((ext_vector_type(8)));
typedef _Float16 halfx8 __attribute__((ext_vector_type(8)));
typedef float floatx4 __attribute__((ext_vector_type(4)));

typedef __attribute__((address_space(1))) void gv_t;
typedef __attribute__((address_space(3))) void lv_t;

// ordered-uint encoding so uint atomicMax == float max (handles both signs)
__device__ __forceinline__ uint32_t fkey(float x) {
  uint32_t b = __float_as_uint(x);
  return (b & 0x80000000u) ? ~b : (b | 0x80000000u);
}
__device__ __forceinline__ float funkey(uint32_t k) {
  uint32_t b = (k & 0x80000000u) ? (k & 0x7fffffffu) : ~k;
  return __uint_as_float(b);
}

// async global->LDS, 16B per lane; lds dst = wave-uniform base, HW adds lane*16
__device__ __forceinline__ void gld_lds16(const void* g, void* lds_uniform) {
  uint32_t loff = (uint32_t)(uintptr_t)lds_uniform;            // low 32b of generic LDS ptr == LDS offset
  loff = (uint32_t)__builtin_amdgcn_readfirstlane((int)loff);  // force wave-uniform
  __builtin_amdgcn_global_load_lds((gv_t*)(uintptr_t)g, (lv_t*)(uintptr_t)loff, 16, 0, 0);
}

// ---------------- init ----------------
__global__ void init_ws(float* v, uint32_t* rowmaxKey, float* scal) {
  int i = blockIdx.x * 256 + threadIdx.x;
  if (i < NN) { v[i] = 1.0f; rowmaxKey[i] = 0u; }
  if (i < 7) ((uint32_t*)scal)[i] = 0u;  // sum, sumsq, mean, inv_std, lossAcc, done, maxdev
}

// ---------------- row normalize + bf16 cast ----------------
__global__ __launch_bounds__(256) void norm_rows(const float* __restrict__ X,
                                                 bf16_t* __restrict__ Y) {
  int tid = threadIdx.x;
  int wave = tid >> 6, lane = tid & 63;
  int row = blockIdx.x * 4 + wave;
  const float* xr = X + (size_t)row * DIM;
  float xv[16];
  float ss = 0.f;
#pragma unroll
  for (int k = 0; k < 16; k++) { xv[k] = xr[lane + 64 * k]; ss += xv[k] * xv[k]; }
#pragma unroll
  for (int off = 1; off < 64; off <<= 1) ss += __shfl_xor(ss, off, 64);
  float inv = rsqrtf(ss);  // norm ~ 32 >> 1e-12 floor, floor never binds
  bf16_t* yr = Y + (size_t)row * DIM;
#pragma unroll
  for (int k = 0; k < 16; k++) yr[lane + 64 * k] = (bf16_t)(xv[k] * inv);
}

// ---------------- GEMM: C = A @ B^T (both row-major, K-contiguous) ----------------
__global__ __launch_bounds__(256) void gemm_bt(const bf16_t* __restrict__ A,
                                               const bf16_t* __restrict__ B,
                                               float* __restrict__ C,
                                               float* __restrict__ scal,
                                               uint32_t* __restrict__ rowmaxKey) {
  __shared__ __align__(16) bf16_t As[128 * 32];
  __shared__ __align__(16) bf16_t Bs[128 * 32];
  int tid = threadIdx.x;
  int wave = tid >> 6, lane = tid & 63;
  int quad = lane >> 4, l16 = lane & 15;
  int bm = blockIdx.y, bn = blockIdx.x;
  int waveM = wave >> 1, waveN = wave & 1;  // 2x2 waves, each 64x64
  floatx4 acc[4][4] = {};

  for (int k0 = 0; k0 < DIM; k0 += 32) {
#pragma unroll
    for (int t = 0; t < 2; t++) {
      int cbase = t * 256 + wave * 64;  // wave-uniform chunk base
      int c = cbase + lane;             // chunk: 16B = 8 bf16
      int row = c >> 2, kc = c & 3;     // tile row, k-subchunk
      gld_lds16(A + (size_t)(bm * 128 + row) * DIM + (k0 + kc * 8), (char*)As + (size_t)cbase * 16);
      gld_lds16(B + (size_t)(bn * 128 + row) * DIM + (k0 + kc * 8), (char*)Bs + (size_t)cbase * 16);
    }
    __syncthreads();  // drains vmcnt before barrier
    bf16x8 af[4], bfr[4];
#pragma unroll
    for (int mt = 0; mt < 4; mt++)
      af[mt] = *(const bf16x8*)(As + (waveM * 64 + mt * 16 + l16) * 32 + quad * 8);
#pragma unroll
    for (int nt = 0; nt < 4; nt++)
      bfr[nt] = *(const bf16x8*)(Bs + (waveN * 64 + nt * 16 + l16) * 32 + quad * 8);
#pragma unroll
    for (int mt = 0; mt < 4; mt++)
#pragma unroll
      for (int nt = 0; nt < 4; nt++)
        acc[mt][nt] = __builtin_amdgcn_mfma_f32_16x16x32_bf16(af[mt], bfr[nt], acc[mt][nt], 0, 0, 0);
    __syncthreads();
  }

  // epilogue: write C (fp32), accumulate sum/sumsq, per-row max
  // C/D layout (m89-verified): col = lane&15, row = quad*4 + reg
  float lsum = 0.f, lsq = 0.f;
#pragma unroll
  for (int mt = 0; mt < 4; mt++) {
#pragma unroll
    for (int r = 0; r < 4; r++) {
      int gi = bm * 128 + waveM * 64 + mt * 16 + quad * 4 + r;
      float rmax = -3.4e38f;
#pragma unroll
      for (int nt = 0; nt < 4; nt++) {
        float vv = acc[mt][nt][r];
        int gj = bn * 128 + waveN * 64 + nt * 16 + l16;
        C[(size_t)gi * NN + gj] = vv;
        lsum += vv;
        lsq += vv * vv;
        rmax = fmaxf(rmax, vv);
      }
#pragma unroll
      for (int off = 1; off < 16; off <<= 1) rmax = fmaxf(rmax, __shfl_xor(rmax, off, 64));
      if (l16 == 0) atomicMax(rowmaxKey + gi, fkey(rmax));
    }
  }
#pragma unroll
  for (int off = 1; off < 64; off <<= 1) {
    lsum += __shfl_xor(lsum, off, 64);
    lsq += __shfl_xor(lsq, off, 64);
  }
  if (lane == 0) { atomicAdd(&scal[0], lsum); atomicAdd(&scal[1], lsq); }
}

// ---------------- mean / inv_std ----------------
__global__ void stats_kernel(float* scal) {
  double sum = (double)scal[0], sumsq = (double)scal[1];
  double N = (double)NN * (double)NN;
  double mean = sum / N;
  double var = (sumsq - sum * sum / N) / (N - 1.0);  // ddof=1
  scal[2] = (float)mean;
  scal[3] = (float)(1.0 / sqrt(var));
}

// ---------------- standardize M in place + build K fp16 ----------------
__global__ __launch_bounds__(256) void build_k(float* __restrict__ M, half_t* __restrict__ K,
                                               const float* __restrict__ scal,
                                               const uint32_t* __restrict__ rowmaxKey) {
  int row = blockIdx.x;
  float mean = scal[2], inv_std = scal[3];
  float rmaxraw = funkey(rowmaxKey[row]);
  float* mrow = M + (size_t)row * NN;
  half_t* krow = K + (size_t)row * NN;
  for (int j = threadIdx.x; j < NN; j += 256) {
    float raw = mrow[j];
    mrow[j] = (raw - mean) * inv_std;                     // M output (standardized)
    krow[j] = (half_t)__expf((raw - rmaxraw) * inv_std);  // K = exp(Mstd - rowmax(Mstd)), gamma=1
  }
}

// ---------------- row matvec: out_i = scale / sum_j K_ij * vin_j ----------------
__global__ __launch_bounds__(256) void row_matvec(const half_t* __restrict__ K,
                                                  const float* __restrict__ vin,
                                                  float* __restrict__ uout,
                                                  float* __restrict__ tzero,
                                                  uint32_t* __restrict__ maxdevBits,
                                                  const uint32_t* __restrict__ done, float scale,
                                                  int gated) {
  if (gated && *done) return;
  int tid = threadIdx.x, wave = tid >> 6, lane = tid & 63;
  int row = blockIdx.x * 4 + wave;
  const halfx8* kr = (const halfx8*)(K + (size_t)row * NN);
  const float4* v4 = (const float4*)vin;
  float acc = 0.f;
#pragma unroll
  for (int s = 0; s < 8; s++) {
    int idx = s * 64 + lane;
    halfx8 kv = kr[idx];
    float4 va = v4[idx * 2], vb = v4[idx * 2 + 1];
    acc += (float)kv[0] * va.x + (float)kv[1] * va.y + (float)kv[2] * va.z + (float)kv[3] * va.w +
           (float)kv[4] * vb.x + (float)kv[5] * vb.y + (float)kv[6] * vb.z + (float)kv[7] * vb.w;
  }
#pragma unroll
  for (int off = 1; off < 64; off <<= 1) acc += __shfl_xor(acc, off, 64);
  if (lane == 0) uout[row] = scale / acc;
  if (tzero && tid < 4) tzero[blockIdx.x * 4 + tid] = 0.f;  // zero col-sum buffer for next pass
  if (maxdevBits && blockIdx.x == 0 && tid == 0) *maxdevBits = 0u;
}

// ---------------- col matvec: tout_j += sum_i uin_i * K_ij (strip + atomics) ----------------
__global__ __launch_bounds__(256) void col_matvec(const half_t* __restrict__ K,
                                                  const float* __restrict__ uin,
                                                  float* __restrict__ tout,
                                                  const uint32_t* __restrict__ done, int gated) {
  if (gated && *done) return;
  int j = blockIdx.x * 256 + threadIdx.x;
  int i0 = blockIdx.y * 128;
  const half_t* kp = K + (size_t)i0 * NN + j;
  float acc = 0.f;
#pragma unroll 4
  for (int i = 0; i < 128; i++) acc += uin[i0 + i] * (float)kp[(size_t)i * NN];
  atomicAdd(tout + j, acc);
}

// ---------------- Sinkhorn update: check convergence, update v ----------------
__global__ __launch_bounds__(1024) void sinkhorn_update(float* __restrict__ v,
                                                        const float* __restrict__ t,
                                                        uint32_t* __restrict__ done) {
  if (*done) return;  // P frozen once converged
  __shared__ float red[16];
  int tid = threadIdx.x;
  float tv[4];
  float md = 0.f;
#pragma unroll
  for (int q = 0; q < 4; q++) {
    int j = tid * 4 + q;
    tv[q] = t[j];
    md = fmaxf(md, fabsf(v[j] * tv[q] - RC));  // beta_j = v_j * (K^T u)_j
  }
#pragma unroll
  for (int off = 1; off < 64; off <<= 1) md = fmaxf(md, __shfl_xor(md, off, 64));
  int wave = tid >> 6, lane = tid & 63;
  if (lane == 0) red[wave] = md;
  __syncthreads();
  if (wave == 0) {
    float m2 = (lane < 16) ? red[lane] : 0.f;
#pragma unroll
    for (int off = 1; off < 16; off <<= 1) m2 = fmaxf(m2, __shfl_xor(m2, off, 64));
    if (lane == 0) red[0] = m2;
  }
  __syncthreads();
  bool new_done = (red[0] <= OT_EPS_F);
  if (!new_done) {
#pragma unroll
    for (int q = 0; q < 4; q++) v[tid * 4 + q] = RC / tv[q];  // col-normalize step
  } else if (tid == 0) {
    *done = 1u;  // converged this iter: keep row-normalized P1 (v unchanged)
  }
}

// ---------------- final P write + loss ----------------
__global__ __launch_bounds__(256) void write_p(const half_t* __restrict__ K,
                                               const float* __restrict__ w,
                                               const float* __restrict__ s,
                                               float* __restrict__ P,
                                               float* __restrict__ lossAcc) {
  int row = blockIdx.x;
  float wi = w[row];
  const half_t* kr = K + (size_t)row * NN;
  float* pr = P + (size_t)row * NN;  // NOTE: d_out+1 base — not 16B aligned, scalar stores only
  float ls = 0.f;
  for (int j = threadIdx.x; j < NN; j += 256) {
    float p = (float)kr[j] * wi / s[j];
    pr[j] = p;
    float d = p - ((j == row) ? 1.0f : 0.0f);
    ls += d * d;
  }
#pragma unroll
  for (int off = 1; off < 64; off <<= 1) ls += __shfl_xor(ls, off, 64);
  __shared__ float r4[4];
  int wave = threadIdx.x >> 6, lane = threadIdx.x & 63;
  if (lane == 0) r4[wave] = ls;
  __syncthreads();
  if (threadIdx.x == 0) atomicAdd(lossAcc, r4[0] + r4[1] + r4[2] + r4[3]);
}

__global__ void final_loss(float* out, const float* lossAcc) { out[0] = sqrtf(*lossAcc); }

// ---------------- launch ----------------
extern "C" void kernel_launch(void* const* d_in, const int* in_sizes, int n_in, void* d_out,
                              int out_size, void* d_ws, size_t ws_size, hipStream_t stream) {
  const float* ft = (const float*)d_in[0];
  const float* fs = (const float*)d_in[1];
  float* out = (float*)d_out;

  char* ws = (char*)d_ws;
  bf16_t* A = (bf16_t*)ws;                          //  8 MiB
  bf16_t* B = (bf16_t*)(ws + (8u << 20));           //  8 MiB
  half_t* K = (half_t*)(ws + (16u << 20));          // 32 MiB
  float* fbase = (float*)(ws + (48u << 20));
  float* v = fbase;
  float* u = fbase + 4096;
  float* t = fbase + 8192;
  float* w = fbase + 12288;
  float* s = fbase + 16384;
  uint32_t* rowmaxKey = (uint32_t*)(fbase + 20480);
  float* scal = fbase + 24576;  // [0]=sum [1]=sumsq [2]=mean [3]=inv_std [4]=lossAcc [5]=done [6]=maxdev
  uint32_t* done = (uint32_t*)(scal + 5);
  uint32_t* maxdevBits = (uint32_t*)(scal + 6);

  float* P_out = out + 1;
  float* M_out = out + 1 + (size_t)NN * NN;  // also scratch for M_raw

  init_ws<<<16, 256, 0, stream>>>(v, rowmaxKey, scal);
  norm_rows<<<1024, 256, 0, stream>>>(ft, A);
  norm_rows<<<1024, 256, 0, stream>>>(fs, B);
  gemm_bt<<<dim3(32, 32), 256, 0, stream>>>(A, B, M_out, scal, rowmaxKey);
  stats_kernel<<<1, 1, 0, stream>>>(scal);
  build_k<<<NN, 256, 0, stream>>>(M_out, K, scal, rowmaxKey);

  for (int it = 0; it < OT_ITERS; it++) {
    row_matvec<<<1024, 256, 0, stream>>>(K, v, u, t, maxdevBits, done, RC, 1);
    col_matvec<<<dim3(16, 32), 256, 0, stream>>>(K, u, t, done, 1);
    sinkhorn_update<<<1, 1024, 0, stream>>>(v, t, done);
  }

  // final: w = 1/(Kv); s = K^T w; P = K_ij * w_i / s_j  (v cancels)
  row_matvec<<<1024, 256, 0, stream>>>(K, v, w, s, nullptr, done, 1.0f, 0);
  col_matvec<<<dim3(16, 32), 256, 0, stream>>>(K, w, s, done, 0);
  write_p<<<NN, 256, 0, stream>>>(K, w, s, P_out, scal + 4);
  final_loss<<<1, 1, 0, stream>>>(out, scal + 4);
}